// Round 1
// baseline (252.366 us; speedup 1.0000x reference)
//
#include <hip/hip_runtime.h>

#define NIMG 4
#define NCLS 19
#define CCH  32
#define LH   128
#define LW   128
#define HH   512
#define WW   512
#define HWQ  (LH*LW)    // 16384 low-res pixels
#define HWP  (HH*WW)    // 262144 hi-res pixels

// Bilinear taps for 128 -> 512 upsample, jax.image.resize half-pixel convention.
// in_coord = (v+0.5)/4 - 0.5 ; edge renormalization == clamping here.
__device__ __forceinline__ void taps(int v, int lim, int& i0, int& i1, float& f) {
    int r = v & 3;
    int b = (v >> 2) + ((r < 2) ? -1 : 0);
    f = 0.125f + 0.25f * (float)((r + 2) & 3);   // r: 0->.625 1->.875 2->.125 3->.375
    i0 = b < 0 ? 0 : b;
    i1 = (b + 1 > lim) ? lim : (b + 1);
}

// K2: scatter per-class bilinear weight field A[n][k][128*128] (global atomics).
__global__ void k_scatter(const int* __restrict__ lab, float* __restrict__ A) {
    int idx = blockIdx.x * 256 + threadIdx.x;
    if (idx >= NIMG * HWP) return;
    int n = idx >> 18;          // / 262144
    int p = idx & (HWP - 1);
    int h = p >> 9, w = p & 511;
    int L = lab[idx];
    int y0, y1, x0, x1; float fy, fx;
    taps(h, LH - 1, y0, y1, fy);
    taps(w, LW - 1, x0, x1, fx);
    float* Ak = A + ((size_t)(n * NCLS + L)) * HWQ;
    float wy0 = 1.f - fy, wx0 = 1.f - fx;
    atomicAdd(&Ak[y0 * LW + x0], wy0 * wx0);
    atomicAdd(&Ak[y0 * LW + x1], wy0 * fx);
    atomicAdd(&Ak[y1 * LW + x0], fy * wx0);
    atomicAdd(&Ak[y1 * LW + x1], fy * fx);
}

// K3: cls_mean[n][k][c] = (sum_q A[n][k][q] * E[n][c][q]) / (count+1); count = sum_q A (exact).
__global__ void k_contract(const float* __restrict__ E, const float* __restrict__ A,
                           float* __restrict__ g_mean, float* __restrict__ g_count) {
    int k = blockIdx.x, n = blockIdx.y;
    int tid = threadIdx.x;
    const float* Ak = A + ((size_t)(n * NCLS + k)) * HWQ;
    const float* En = E + (size_t)n * CCH * HWQ;
    float acc[CCH];
#pragma unroll
    for (int c = 0; c < CCH; c++) acc[c] = 0.f;
    float cnt = 0.f;
    for (int q = tid; q < HWQ; q += 256) {
        float a = Ak[q];
        cnt += a;
#pragma unroll
        for (int c = 0; c < CCH; c++) acc[c] += a * En[c * HWQ + q];
    }
#pragma unroll
    for (int s = 1; s < 64; s <<= 1) {
        cnt += __shfl_xor(cnt, s);
#pragma unroll
        for (int c = 0; c < CCH; c++) acc[c] += __shfl_xor(acc[c], s);
    }
    __shared__ float lds[4][CCH];
    __shared__ float ldsc[4];
    int wave = tid >> 6, lane = tid & 63;
    if (lane == 0) {
        for (int c = 0; c < CCH; c++) lds[wave][c] = acc[c];
        ldsc[wave] = cnt;
    }
    __syncthreads();
    if (tid < CCH) {
        float s = lds[0][tid] + lds[1][tid] + lds[2][tid] + lds[3][tid];
        float ct = ldsc[0] + ldsc[1] + ldsc[2] + ldsc[3];
        g_mean[(n * NCLS + k) * CCH + tid] = s / (ct + 1.f);
        if (tid == 0) g_count[n * NCLS + k] = ct;
    }
}

// K5: intra_acc[n][k] = sum over pixels of class k of mean_c (emb - mean_k)^2
__global__ void k_intra(const float* __restrict__ E, const int* __restrict__ lab,
                        const float* __restrict__ g_mean, float* __restrict__ g_intra) {
    int n = blockIdx.y;
    __shared__ float m[NCLS * 33];   // stride-33 pad: bank = (L+c)%32, spreads random L
    __shared__ float acc[32];
    for (int i = threadIdx.x; i < NCLS * CCH; i += 256) {
        int L = i >> 5, c = i & 31;
        m[L * 33 + c] = g_mean[n * NCLS * CCH + i];
    }
    if (threadIdx.x < 32) acc[threadIdx.x] = 0.f;
    __syncthreads();

    const float* eb = E + (size_t)n * CCH * HWQ;
    const int* ln = lab + (size_t)n * HWP;
    int stride = gridDim.x * 256;
    for (int p = blockIdx.x * 256 + threadIdx.x; p < HWP; p += stride) {
        int h = p >> 9, w = p & 511;
        int y0, y1, x0, x1; float fy, fx;
        taps(h, LH - 1, y0, y1, fy);
        taps(w, LW - 1, x0, x1, fx);
        float wy0 = 1.f - fy, wx0 = 1.f - fx;
        float w00 = wy0 * wx0, w01 = wy0 * fx, w10 = fy * wx0, w11 = fy * fx;
        int b00 = y0 * LW + x0, b01 = y0 * LW + x1, b10 = y1 * LW + x0, b11 = y1 * LW + x1;
        int L = ln[p];
        const float* mr = m + L * 33;
        float d = 0.f;
#pragma unroll 8
        for (int c = 0; c < CCH; c++) {
            int off = c << 14;
            float v = w00 * eb[off + b00] + w01 * eb[off + b01]
                    + w10 * eb[off + b10] + w11 * eb[off + b11];
            float t = v - mr[c];
            d += t * t;
        }
        atomicAdd(&acc[L], d * (1.f / 32.f));
    }
    __syncthreads();
    if (threadIdx.x < NCLS) atomicAdd(&g_intra[n * NCLS + threadIdx.x], acc[threadIdx.x]);
}

// K6: final per-image reduction -> out[n]
__global__ void k_final(const float* __restrict__ g_mean, const float* __restrict__ g_count,
                        const float* __restrict__ g_intra, float* __restrict__ out) {
    int n = blockIdx.x, t = threadIdx.x;   // 64 threads
    __shared__ float m[NCLS * CCH];
    __shared__ float cnt[NCLS];
    __shared__ float intra[NCLS];
    for (int i = t; i < NCLS * CCH; i += 64) m[i] = g_mean[n * NCLS * CCH + i];
    if (t < NCLS) { cnt[t] = g_count[n * NCLS + t]; intra[t] = g_intra[n * NCLS + t]; }
    __syncthreads();
    float nfg = 0.f;
    for (int k = 1; k < NCLS; k++) nfg += (cnt[k] > 0.f) ? 1.f : 0.f;
    float vi = 0.f;
    if (t >= 1 && t < NCLS && cnt[t] > 0.f) vi = intra[t] / (cnt[t] + 1.f);
    float ve = 0.f;
    for (int pidx = t; pidx < 18 * 18; pidx += 64) {
        int j = 1 + pidx / 18, k = 1 + pidx % 18;
        if (cnt[j] > 0.f && cnt[k] > 0.f) {
            float s = 0.f;
            for (int c = 0; c < CCH; c++) {
                float d = m[j * CCH + c] - m[k * CCH + c];
                s += d * d;
            }
            ve += s * (1.f / 32.f);
        }
    }
#pragma unroll
    for (int s = 32; s >= 1; s >>= 1) { vi += __shfl_xor(vi, s); ve += __shfl_xor(ve, s); }
    if (t == 0) out[n] = vi / nfg - ve / (nfg * nfg);
}

extern "C" void kernel_launch(void* const* d_in, const int* in_sizes, int n_in,
                              void* d_out, int out_size, void* d_ws, size_t ws_size,
                              hipStream_t stream) {
    const float* E = (const float*)d_in[0];   // (4,32,128,128) fp32
    const int* lab = (const int*)d_in[1];     // (4,512,512) int
    float* out = (float*)d_out;               // (4,) fp32

    float* ws = (float*)d_ws;
    const size_t A_elems = (size_t)NIMG * NCLS * HWQ;         // 1,245,184
    float* A       = ws;
    float* g_intra = ws + A_elems;                            // 76
    float* g_count = g_intra + NIMG * NCLS;                   // 76
    float* g_mean  = g_count + NIMG * NCLS;                   // 2432

    // zero A + g_intra (g_count/g_mean are fully overwritten)
    hipMemsetAsync(d_ws, 0, (A_elems + 2 * NIMG * NCLS) * sizeof(float), stream);

    k_scatter<<<dim3((NIMG * HWP) / 256), dim3(256), 0, stream>>>(lab, A);
    k_contract<<<dim3(NCLS, NIMG), dim3(256), 0, stream>>>(E, A, g_mean, g_count);
    k_intra<<<dim3(256, NIMG), dim3(256), 0, stream>>>(E, lab, g_mean, g_intra);
    k_final<<<dim3(NIMG), dim3(64), 0, stream>>>(g_mean, g_count, g_intra, out);
}

// Round 2
// 119.567 us; speedup vs baseline: 2.1107x; 2.1107x over previous
//
#include <hip/hip_runtime.h>

#define NIMG 4
#define NCLS 19
#define CCH  32
#define LH   128
#define LW   128
#define HH   512
#define WW   512
#define HWQ  (LH*LW)    // 16384 low-res pixels
#define HWP  (HH*WW)    // 262144 hi-res pixels

// k_field tiling: each block OWNS a disjoint TRxTC low-res region
#define TR 8
#define TC 16
#define NTX (LW/TC)       // 8
#define NTY (LH/TR)       // 16
#define NTILE (NTY*NTX)   // 128 blocks per image
#define TCELLS (TR*TC)    // 128
#define HALO_R (TR*4+4)   // 36
#define HALO_C (TC*4+4)   // 68

#define QB 64             // k_quad blocks per image (16384 quads / 256)

// Bilinear taps for 128 -> 512 upsample, jax.image.resize half-pixel convention.
__device__ __forceinline__ void taps(int v, int lim, int& i0, int& i1, float& f) {
    int r = v & 3;
    int b = (v >> 2) + ((r < 2) ? -1 : 0);
    f = 0.125f + 0.25f * (float)((r + 2) & 3);   // r: 0->.625 1->.875 2->.125 3->.375
    i0 = b < 0 ? 0 : b;
    i1 = (b + 1 > lim) ? lim : (b + 1);
}

// K1: per-tile A-field in LDS (gather, zero global atomics) + fused contract:
//   P_sum[n][tile][k][c] = sum_{cells in tile} A[k][cell] * E[c][cell]
//   P_cnt[n][tile][k]    = sum_{cells} A[k][cell]   (exact: dyadic weights)
__global__ __launch_bounds__(256) void k_field(const float* __restrict__ E,
        const int* __restrict__ lab, float* __restrict__ P_sum, float* __restrict__ P_cnt) {
    int tile = blockIdx.x, n = blockIdx.y;
    int ty = tile >> 3, tx = tile & 7;          // NTX=8
    int Y0 = ty * TR, X0 = tx * TC;
    __shared__ float A[TCELLS * NCLS];          // [cell][k], stride 19 (coprime w/ 32 banks)
    __shared__ float red[8 * NCLS * CCH];       // [g][k][c] contract partials
    int tid = threadIdx.x;
    for (int i = tid; i < TCELLS * NCLS; i += 256) A[i] = 0.f;
    __syncthreads();

    // gather halo pixels; keep only taps landing in the owned region
    const int* ln = lab + (size_t)n * HWP;
    int h_lo = Y0 * 4 - 2, w_lo = X0 * 4 - 2;
    for (int i = tid; i < HALO_R * HALO_C; i += 256) {
        int hr = i / HALO_C, wc = i - hr * HALO_C;
        int h = h_lo + hr, w = w_lo + wc;
        if (h < 0 || h >= HH || w < 0 || w >= WW) continue;
        int L = ln[h * WW + w];
        int y0, y1, x0, x1; float fy, fx;
        taps(h, LH - 1, y0, y1, fy);
        taps(w, LW - 1, x0, x1, fx);
        int yy[2] = {y0, y1}; float wy[2] = {1.f - fy, fy};
        int xx[2] = {x0, x1}; float wx[2] = {1.f - fx, fx};
#pragma unroll
        for (int a = 0; a < 2; a++) {
#pragma unroll
            for (int b = 0; b < 2; b++) {
                int ry = yy[a] - Y0, rx = xx[b] - X0;
                if (ry >= 0 && ry < TR && rx >= 0 && rx < TC)
                    atomicAdd(&A[(ry * TC + rx) * NCLS + L], wy[a] * wx[b]);
            }
        }
    }
    __syncthreads();

    // fused contract: thread (g,c); A reads are wave-uniform broadcasts
    int g = tid >> 5, c = tid & 31;
    const float* Ec = E + ((size_t)n * CCH + c) * HWQ;
    float acc[NCLS];
#pragma unroll
    for (int k = 0; k < NCLS; k++) acc[k] = 0.f;
#pragma unroll
    for (int j = 0; j < TCELLS / 8; j++) {
        int cell = g * (TCELLS / 8) + j;
        int cy = cell >> 4, cx = cell & 15;     // TC=16
        float e = Ec[(Y0 + cy) * LW + (X0 + cx)];
        const float* Ar = &A[cell * NCLS];
#pragma unroll
        for (int k = 0; k < NCLS; k++) acc[k] = fmaf(Ar[k], e, acc[k]);
    }
#pragma unroll
    for (int k = 0; k < NCLS; k++) red[(g * NCLS + k) * CCH + c] = acc[k];
    __syncthreads();

    float* Ps = P_sum + (size_t)(n * NTILE + tile) * (NCLS * CCH);
    for (int idx = tid; idx < NCLS * CCH; idx += 256) {
        float s = 0.f;
#pragma unroll
        for (int gg = 0; gg < 8; gg++) s += red[gg * NCLS * CCH + idx];
        Ps[idx] = s;
    }
    if (tid < NCLS) {
        float s = 0.f;
        for (int cell = 0; cell < TCELLS; cell++) s += A[cell * NCLS + tid];
        P_cnt[(size_t)(n * NTILE + tile) * NCLS + tid] = s;
    }
}

// K2: S2[n][k] = sum over pixels of class k of ||v_p||^2  (v = upsampled embedding)
// one thread per 4x4 hi-res quad: 9 low-res cells per channel, separable lerps.
__global__ __launch_bounds__(256) void k_quad(const float* __restrict__ E,
        const int* __restrict__ lab, float* __restrict__ P_S2) {
    int n = blockIdx.y;
    int q = blockIdx.x * 256 + threadIdx.x;     // quad id in [0,16384)
    int by = q >> 7, bx = q & 127;
    __shared__ float accS2[NCLS];
    if (threadIdx.x < NCLS) accS2[threadIdx.x] = 0.f;
    __syncthreads();

    const float* En = E + (size_t)n * CCH * HWQ;
    int r0 = (by == 0) ? 0 : by - 1;
    int r2 = (by == LH - 1) ? LH - 1 : by + 1;
    int c0 = (bx == 0) ? 0 : bx - 1;
    int c2 = (bx == LW - 1) ? LW - 1 : bx + 1;
    int o0 = r0 * LW, o1 = by * LW, o2 = r2 * LW;

    float d2[16];
#pragma unroll
    for (int i = 0; i < 16; i++) d2[i] = 0.f;

    for (int c = 0; c < CCH; c++) {
        const float* Ep = En + (size_t)c * HWQ;
        float e00 = Ep[o0 + c0], e01 = Ep[o0 + bx], e02 = Ep[o0 + c2];
        float e10 = Ep[o1 + c0], e11 = Ep[o1 + bx], e12 = Ep[o1 + c2];
        float e20 = Ep[o2 + c0], e21 = Ep[o2 + bx], e22 = Ep[o2 + c2];
        // y-lerps: r=0,1 between rows(0,1) f=.625/.875 ; r=2,3 between rows(1,2) f=.125/.375
        float dy0 = e10 - e00, dy1 = e11 - e01, dy2 = e12 - e02;
        float dz0 = e20 - e10, dz1 = e21 - e11, dz2 = e22 - e12;
        float ry[4][3];
        ry[0][0] = fmaf(0.625f, dy0, e00); ry[0][1] = fmaf(0.625f, dy1, e01); ry[0][2] = fmaf(0.625f, dy2, e02);
        ry[1][0] = fmaf(0.875f, dy0, e00); ry[1][1] = fmaf(0.875f, dy1, e01); ry[1][2] = fmaf(0.875f, dy2, e02);
        ry[2][0] = fmaf(0.125f, dz0, e10); ry[2][1] = fmaf(0.125f, dz1, e11); ry[2][2] = fmaf(0.125f, dz2, e12);
        ry[3][0] = fmaf(0.375f, dz0, e10); ry[3][1] = fmaf(0.375f, dz1, e11); ry[3][2] = fmaf(0.375f, dz2, e12);
#pragma unroll
        for (int r = 0; r < 4; r++) {
            float da = ry[r][1] - ry[r][0], db = ry[r][2] - ry[r][1];
            float v0 = fmaf(0.625f, da, ry[r][0]);
            float v1 = fmaf(0.875f, da, ry[r][0]);
            float v2 = fmaf(0.125f, db, ry[r][1]);
            float v3 = fmaf(0.375f, db, ry[r][1]);
            d2[r * 4 + 0] = fmaf(v0, v0, d2[r * 4 + 0]);
            d2[r * 4 + 1] = fmaf(v1, v1, d2[r * 4 + 1]);
            d2[r * 4 + 2] = fmaf(v2, v2, d2[r * 4 + 2]);
            d2[r * 4 + 3] = fmaf(v3, v3, d2[r * 4 + 3]);
        }
    }
    const int* lp = lab + (size_t)n * HWP + (by * 4) * WW + bx * 4;
#pragma unroll
    for (int r = 0; r < 4; r++) {
        int4 l4 = *(const int4*)(lp + r * WW);
        atomicAdd(&accS2[l4.x], d2[r * 4 + 0]);
        atomicAdd(&accS2[l4.y], d2[r * 4 + 1]);
        atomicAdd(&accS2[l4.z], d2[r * 4 + 2]);
        atomicAdd(&accS2[l4.w], d2[r * 4 + 3]);
    }
    __syncthreads();
    if (threadIdx.x < NCLS)
        P_S2[(size_t)(n * QB + blockIdx.x) * NCLS + threadIdx.x] = accS2[threadIdx.x];
}

// K3: reduce partials, intra via S2 - 2 m.s + cnt |m|^2, inter pairwise, output
__global__ __launch_bounds__(384) void k_final(const float* __restrict__ P_sum,
        const float* __restrict__ P_cnt, const float* __restrict__ P_S2,
        float* __restrict__ out) {
    int n = blockIdx.x, t = threadIdx.x;
    __shared__ float csum[NCLS * 33];   // stride-33 pad
    __shared__ float m[NCLS * 33];
    __shared__ float cnt[NCLS];
    __shared__ float S2[NCLS];
    __shared__ float sIntra, sNfg, sInter;

    if (t == 0) sInter = 0.f;
    if (t < NCLS) {
        float s = 0.f;
        const float* p = P_cnt + (size_t)n * NTILE * NCLS + t;
        for (int b = 0; b < NTILE; b++) s += p[b * NCLS];
        cnt[t] = s;
        float s2 = 0.f;
        const float* p2 = P_S2 + (size_t)n * QB * NCLS + t;
        for (int b = 0; b < QB; b++) s2 += p2[b * NCLS];
        S2[t] = s2;
    }
    for (int idx = t; idx < NCLS * CCH; idx += 384) {
        float s = 0.f;
        const float* p = P_sum + (size_t)n * NTILE * NCLS * CCH + idx;
        for (int b = 0; b < NTILE; b++) s += p[b * NCLS * CCH];
        csum[(idx >> 5) * 33 + (idx & 31)] = s;
    }
    __syncthreads();
    for (int idx = t; idx < NCLS * CCH; idx += 384) {
        int k = idx >> 5, c = idx & 31;
        m[k * 33 + c] = csum[k * 33 + c] / (cnt[k] + 1.f);
    }
    __syncthreads();

    // intra + n_fg (all of t<19 sits in wave 0)
    float vi = 0.f, fg = 0.f;
    if (t >= 1 && t < NCLS && cnt[t] > 0.f) {
        fg = 1.f;
        float dot = 0.f, mm = 0.f;
        for (int c = 0; c < CCH; c++) {
            float mv = m[t * 33 + c];
            dot = fmaf(mv, csum[t * 33 + c], dot);
            mm = fmaf(mv, mv, mm);
        }
        vi = (S2[t] - 2.f * dot + cnt[t] * mm) * (1.f / 32.f) / (cnt[t] + 1.f);
    }
#pragma unroll
    for (int s_ = 32; s_ >= 1; s_ >>= 1) { vi += __shfl_xor(vi, s_); fg += __shfl_xor(fg, s_); }
    if (t == 0) { sIntra = vi; sNfg = fg; }

    // inter: 18x18 foreground pairs
    float ve = 0.f;
    if (t < 324) {
        int j = 1 + t / 18, k = 1 + t % 18;
        if (cnt[j] > 0.f && cnt[k] > 0.f) {
            float s = 0.f;
            for (int c = 0; c < CCH; c++) {
                float d = m[j * 33 + c] - m[k * 33 + c];
                s = fmaf(d, d, s);
            }
            ve = s * (1.f / 32.f);
        }
    }
#pragma unroll
    for (int s_ = 32; s_ >= 1; s_ >>= 1) ve += __shfl_xor(ve, s_);
    if ((t & 63) == 0) atomicAdd(&sInter, ve);
    __syncthreads();
    if (t == 0) out[n] = sIntra / sNfg - sInter / (sNfg * sNfg);
}

extern "C" void kernel_launch(void* const* d_in, const int* in_sizes, int n_in,
                              void* d_out, int out_size, void* d_ws, size_t ws_size,
                              hipStream_t stream) {
    const float* E = (const float*)d_in[0];   // (4,32,128,128) fp32
    const int* lab = (const int*)d_in[1];     // (4,512,512) int
    float* out = (float*)d_out;               // (4,) fp32

    float* ws = (float*)d_ws;
    float* P_sum = ws;                                        // 4*128*608
    float* P_cnt = P_sum + (size_t)NIMG * NTILE * NCLS * CCH; // 4*128*19
    float* P_S2  = P_cnt + (size_t)NIMG * NTILE * NCLS;       // 4*64*19
    // all partial slots are fully overwritten every call -> no memset needed

    k_field<<<dim3(NTILE, NIMG), dim3(256), 0, stream>>>(E, lab, P_sum, P_cnt);
    k_quad <<<dim3(QB, NIMG),    dim3(256), 0, stream>>>(E, lab, P_S2);
    k_final<<<dim3(NIMG),        dim3(384), 0, stream>>>(P_sum, P_cnt, P_S2, out);
}